// Round 1
// baseline (858.955 us; speedup 1.0000x reference)
//
#include <hip/hip_runtime.h>
#include <hip/hip_bf16.h>

typedef __bf16 bf16x8 __attribute__((ext_vector_type(8)));
typedef float f32x4 __attribute__((ext_vector_type(4)));
typedef unsigned short ushort_t;

#define NN 8192
#define DD 128
#define KTOT 24576
#define SPLITS 8
#define KSPLIT 3072   // KTOT / SPLITS
#define BM 128

// ---------------------------------------------------------------------------
// Kernel 1: B[r][n] = sum_c x[r&8191][c] * sd[r>>13][c] * W[c][n]  (r in [0,24576))
// Output bf16, stored in MFMA-16x16x32 B-fragment order:
//   Bws[(((r>>5)*8 + (n>>4))*64 + ((r>>3 & 3)*16 + (n&15)))*8 + (r&7)]
// so the main kernel reads each fragment as one coalesced 16B load per lane.
// ---------------------------------------------------------------------------
__global__ __launch_bounds__(256) void bprep_kernel(
    const float* __restrict__ x, const float* __restrict__ W,
    const float* __restrict__ sd0, const float* __restrict__ sd1,
    const float* __restrict__ sd2, ushort_t* __restrict__ Bws)
{
    const int tid = threadIdx.x;
    const int n  = tid & 127;
    const int rg = tid >> 7;                 // 0..1, each handles 8 rows
    const int r0 = blockIdx.x * 16;          // 16 rows per block, never crosses a support
    const int sup = r0 >> 13;
    const float* sd = (sup == 0) ? sd0 : ((sup == 1) ? sd1 : sd2);
    const int xrow0 = (r0 & (NN - 1)) + rg * 8;

    float acc[8];
#pragma unroll
    for (int i = 0; i < 8; ++i) acc[i] = 0.f;

    for (int c = 0; c < DD; ++c) {
        float wv = sd[c] * W[c * DD + n];
#pragma unroll
        for (int i = 0; i < 8; ++i)
            acc[i] = fmaf(x[(size_t)(xrow0 + i) * DD + c], wv, acc[i]);
    }

    const int t = n >> 4;
    const int nlo = n & 15;
#pragma unroll
    for (int i = 0; i < 8; ++i) {
        int r   = r0 + rg * 8 + i;
        int cc  = r >> 5;                    // global 32-wide k-chunk
        int rem = r & 31;
        int hi  = rem >> 3;                  // lane>>4 quadrant
        int j   = rem & 7;                   // element within fragment
        int ll  = hi * 16 + nlo;             // lane
        size_t idx = (((size_t)cc * 8 + t) * 64 + ll) * 8 + j;
        __bf16 b = (__bf16)acc[i];
        ushort_t u;
        __builtin_memcpy(&u, &b, sizeof(u));
        Bws[idx] = u;
    }
}

// ---------------------------------------------------------------------------
// Kernel 2: out += S_cat[8192 x 24576] @ B_cat[24576 x 128]  (split-K atomics)
// No LDS / no barriers: A fragments (fp32->bf16) straight from HBM,
// B fragments from L1/L2 (6.3 MB working set), fp32 atomicAdd epilogue.
// ---------------------------------------------------------------------------
__global__ __launch_bounds__(256, 2) void spmm_kernel(
    const float* __restrict__ s0, const float* __restrict__ s1,
    const float* __restrict__ s2, const ushort_t* __restrict__ Bws,
    float* __restrict__ out)
{
    const int lane  = threadIdx.x & 63;
    const int wave  = threadIdx.x >> 6;
    const int split = blockIdx.x & (SPLITS - 1);
    const int mblk  = blockIdx.x >> 3;
    const int kbase = split * KSPLIT;
    const int m15   = lane & 15;
    const int q     = lane >> 4;
    const int row0  = mblk * BM + wave * 32;   // wave: rows [row0, row0+32)

    f32x4 acc[2][8];
#pragma unroll
    for (int ms = 0; ms < 2; ++ms)
#pragma unroll
        for (int t = 0; t < 8; ++t)
            acc[ms][t] = (f32x4){0.f, 0.f, 0.f, 0.f};

    const bf16x8* __restrict__ Bv = reinterpret_cast<const bf16x8*>(Bws);
    const int nsub = KSPLIT / 32;              // 96 k-steps of 32
    const int cg0  = kbase >> 5;

#pragma unroll 2
    for (int c = 0; c < nsub; ++c) {
        const int kg  = kbase + c * 32;
        const int sup = kg >> 13;
        const float* sp = (sup == 0) ? s0 : ((sup == 1) ? s1 : s2);
        const int koff = (kg & (NN - 1)) + q * 8;

        bf16x8 af[2];
#pragma unroll
        for (int ms = 0; ms < 2; ++ms) {
            const float* ap = sp + (size_t)(row0 + ms * 16 + m15) * NN + koff;
            float4 f0 = *reinterpret_cast<const float4*>(ap);
            float4 f1 = *reinterpret_cast<const float4*>(ap + 4);
            bf16x8 a;
            a[0] = (__bf16)f0.x; a[1] = (__bf16)f0.y;
            a[2] = (__bf16)f0.z; a[3] = (__bf16)f0.w;
            a[4] = (__bf16)f1.x; a[5] = (__bf16)f1.y;
            a[6] = (__bf16)f1.z; a[7] = (__bf16)f1.w;
            af[ms] = a;
        }

        const bf16x8* bp = Bv + (size_t)(cg0 + c) * 8 * 64 + lane;
#pragma unroll
        for (int t = 0; t < 8; ++t) {
            bf16x8 bf = bp[(size_t)t * 64];
            acc[0][t] = __builtin_amdgcn_mfma_f32_16x16x32_bf16(af[0], bf, acc[0][t], 0, 0, 0);
            acc[1][t] = __builtin_amdgcn_mfma_f32_16x16x32_bf16(af[1], bf, acc[1][t], 0, 0, 0);
        }
    }

    // C/D layout (m89-verified): col = lane&15, row = (lane>>4)*4 + reg
#pragma unroll
    for (int ms = 0; ms < 2; ++ms)
#pragma unroll
        for (int t = 0; t < 8; ++t)
#pragma unroll
            for (int r = 0; r < 4; ++r) {
                int row = row0 + ms * 16 + q * 4 + r;
                int col = t * 16 + m15;
                atomicAdd(out + (size_t)row * DD + col, acc[ms][t][r]);
            }
}

// ---------------------------------------------------------------------------
// Kernel 3: in-place relu on d_out
// ---------------------------------------------------------------------------
__global__ __launch_bounds__(256) void relu_kernel(float4* __restrict__ out)
{
    int i = blockIdx.x * 256 + threadIdx.x;
    float4 v = out[i];
    v.x = fmaxf(v.x, 0.f);
    v.y = fmaxf(v.y, 0.f);
    v.z = fmaxf(v.z, 0.f);
    v.w = fmaxf(v.w, 0.f);
    out[i] = v;
}

extern "C" void kernel_launch(void* const* d_in, const int* in_sizes, int n_in,
                              void* d_out, int out_size, void* d_ws, size_t ws_size,
                              hipStream_t stream)
{
    (void)in_sizes; (void)n_in; (void)ws_size;
    const float* x   = (const float*)d_in[0];
    const float* s0  = (const float*)d_in[1];
    const float* s1  = (const float*)d_in[2];
    const float* s2  = (const float*)d_in[3];
    const float* W   = (const float*)d_in[4];
    const float* sd0 = (const float*)d_in[5];
    const float* sd1 = (const float*)d_in[6];
    const float* sd2 = (const float*)d_in[7];
    float* out = (float*)d_out;
    ushort_t* Bws = (ushort_t*)d_ws;   // needs 24576*128*2 = 6.3 MB

    // d_out is poisoned before every launch -> zero it for the atomic accumulate
    hipMemsetAsync(d_out, 0, (size_t)out_size * sizeof(float), stream);
    bprep_kernel<<<KTOT / 16, 256, 0, stream>>>(x, W, sd0, sd1, sd2, Bws);
    spmm_kernel<<<(NN / BM) * SPLITS, 256, 0, stream>>>(s0, s1, s2, Bws, out);
    relu_kernel<<<out_size / 1024, 256, 0, stream>>>((float4*)d_out);
}